// Round 5
// baseline (1347.146 us; speedup 1.0000x reference)
//
#include <hip/hip_runtime.h>
#include <math.h>

#define DIM_ 2048
#define KTOP 8
#define MSLOT 16
#define TSTEPS 256
#define NB 64
#define NTHREADS 320 // 5 waves: wave0 = serial wave, waves 1..4 = workers
#define NWORK 256
#define EPT 8
#define CCAP 128

static_assert(NWORK * EPT == DIM_, "mapping");

#define DPP0(src, ctrl, rm) __builtin_amdgcn_update_dpp(0, (src), (ctrl), (rm), 0xf, true)

// ---- f64 packed-key helpers (key = f32bits(|c|) : ~index, never NaN) ----
__device__ __forceinline__ void ced(double &a, double &b) {
  double mx = fmax(a, b);
  b = fmin(a, b);
  a = mx;
}

// 4-element descending sort of k[0..3] (5 CE)
__device__ __forceinline__ void sort4d(double k[8]) {
  ced(k[0],k[1]); ced(k[2],k[3]);
  ced(k[0],k[2]); ced(k[1],k[3]);
  ced(k[1],k[2]);
}

// merge own sorted-2 (k[0..1]) with partner's sorted-2 -> sorted-4 in k[0..3]
template <int CTRL, int RM>
__device__ __forceinline__ void merge_2to4_d(double k[8]) {
  int lo0 = DPP0(__double2loint(k[0]), CTRL, RM);
  int hi0 = DPP0(__double2hiint(k[0]), CTRL, RM);
  int lo1 = DPP0(__double2loint(k[1]), CTRL, RM);
  int hi1 = DPP0(__double2hiint(k[1]), CTRL, RM);
  double b0 = __hiloint2double(hi0, lo0);
  double b1 = __hiloint2double(hi1, lo1);
  double z2 = b1, z3 = b0; // bitonic: [k0,k1,b1,b0]
  ced(k[0], z2); ced(k[1], z3);
  ced(k[0], k[1]); ced(z2, z3);
  k[2] = z2; k[3] = z3;
}

// merge own sorted-4 (k[0..3]) with partner's sorted-4 -> sorted-8
template <int CTRL, int RM>
__device__ __forceinline__ void merge_first4(double k[8]) {
  double b[4];
#pragma unroll
  for (int i = 0; i < 4; i++) {
    int lo = DPP0(__double2loint(k[i]), CTRL, RM);
    int hi = DPP0(__double2hiint(k[i]), CTRL, RM);
    b[i] = __hiloint2double(hi, lo);
  }
  k[4] = b[3]; k[5] = b[2]; k[6] = b[1]; k[7] = b[0]; // bitonic sequence
  ced(k[0],k[4]); ced(k[1],k[5]); ced(k[2],k[6]); ced(k[3],k[7]);
  ced(k[0],k[2]); ced(k[1],k[3]); ced(k[4],k[6]); ced(k[5],k[7]);
  ced(k[0],k[1]); ced(k[2],k[3]); ced(k[4],k[5]); ced(k[6],k[7]);
}

// pull partner's sorted-8, keep top-8 of union, resort desc
template <int CTRL, int RM>
__device__ __forceinline__ void merge_level(double k[8]) {
  double b[8];
#pragma unroll
  for (int i = 0; i < 8; i++) {
    int lo = DPP0(__double2loint(k[i]), CTRL, RM);
    int hi = DPP0(__double2hiint(k[i]), CTRL, RM);
    b[i] = __hiloint2double(hi, lo);
  }
#pragma unroll
  for (int i = 0; i < 8; i++) k[i] = fmax(k[i], b[7 - i]);
  ced(k[0],k[4]); ced(k[1],k[5]); ced(k[2],k[6]); ced(k[3],k[7]);
  ced(k[0],k[2]); ced(k[1],k[3]); ced(k[4],k[6]); ced(k[5],k[7]);
  ced(k[0],k[1]); ced(k[2],k[3]); ced(k[4],k[5]); ced(k[6],k[7]);
}

#define FMAX_STAGE(x, ctrl, rm)                                                \
  x = fmaxf(x, __int_as_float(DPP0(__float_as_int(x), ctrl, rm)))
#define FADD_STAGE(x, ctrl, rm)                                                \
  x = x + __int_as_float(DPP0(__float_as_int(x), ctrl, rm))

__device__ __forceinline__ float wave_max_f32(float x) {
  FMAX_STAGE(x, 0x111, 0xf);
  FMAX_STAGE(x, 0x112, 0xf);
  FMAX_STAGE(x, 0x114, 0xf);
  FMAX_STAGE(x, 0x118, 0xf);
  FMAX_STAGE(x, 0x142, 0xa);
  FMAX_STAGE(x, 0x143, 0xc);
  return x; // lane 63 has the max
}
__device__ __forceinline__ float wave_sum_f32(float x) {
  FADD_STAGE(x, 0x111, 0xf);
  FADD_STAGE(x, 0x112, 0xf);
  FADD_STAGE(x, 0x114, 0xf);
  FADD_STAGE(x, 0x118, 0xf);
  FADD_STAGE(x, 0x142, 0xa);
  FADD_STAGE(x, 0x143, 0xc);
  return x; // lane 63 has the sum
}
__device__ __forceinline__ int rl63(int v) {
  return __builtin_amdgcn_readlane(v, 63);
}

__global__ void __launch_bounds__(NTHREADS)
me_fused(const float *__restrict__ x, const float *__restrict__ tape_re,
         const float *__restrict__ tape_im, const float *__restrict__ eta_param,
         const float *__restrict__ tbias_re, const float *__restrict__ tbias_im,
         float *__restrict__ out) {
  __shared__ float4 sc4[DIM_];                 // (h, vre, vim, 0)
  __shared__ float2 dxy[DIM_];                 // scatter deltas
  __shared__ __align__(16) uint2 lmax2[NWORK]; // per-thread max (avbits, ~e)
  __shared__ unsigned long long cand_lds[CCAP];// [0..7]=top8 (rare), [8..]=extras
  __shared__ int extra_cnt;                    // extras appended this step
  __shared__ int theta_flag;                   // monotone: t+1 when theta ready
  __shared__ int extras_done;                  // monotone: 4*(t+1) when all in
  __shared__ unsigned int theta_hi_sh, theta_lo_sh;
  __shared__ float red_sh[4];                  // norm^2 partials

  const int tid = threadIdx.x;
  const int lane = tid & 63;
  const int wid = tid >> 6;
  const int wtid = tid - 64; // worker element base (valid for wid>0)
  const int b = blockIdx.x;

  const float eta = fabsf(eta_param[0]);

  float vre[EPT], vim[EPT], tbre_[EPT], tbim_[EPT];
  float hcur[EPT], hnext[EPT], av[EPT];
  float osr[EPT], osi[EPT];
  unsigned int lmlo = 0; // ~e of this thread's argmax element
  const float *xb = x + (size_t)b * TSTEPS * DIM_;

  // ---- prologue: establish step-0 invariants ----
  if (tid == 0) { extra_cnt = 0; theta_flag = 0; extras_done = 0; }
  if (wid > 0) {
    float acc = 0.f, lm = -1.f;
#pragma unroll
    for (int j = 0; j < EPT; j++) {
      int e = wtid + NWORK * j;
      float a = tape_re[e], c2 = tape_im[e];
      vre[j] = a; vim[j] = c2;
      tbre_[j] = tbias_re[e]; tbim_[j] = tbias_im[e];
      float h = xb[e];
      hcur[j] = h; hnext[j] = h;
      dxy[e] = make_float2(0.f, 0.f);
      acc += a * a + c2 * c2;
      float cr = h * a, ci = h * c2;
      av[j] = sqrtf(cr * cr + ci * ci); // scale-invariant ordering key
      unsigned int lo = ~(unsigned int)e;
      if (av[j] > lm || (av[j] == lm && lo > lmlo)) { lm = av[j]; lmlo = lo; }
      sc4[e] = make_float4(h, a, c2, 0.f);
    }
    float ws = wave_sum_f32(acc);
    if (lane == 63) red_sh[wid - 1] = ws;
    lmax2[wtid] = make_uint2((unsigned int)__float_as_int(lm), lmlo);
  }

  // transient slots live in wave0 registers (lanes 0..15)
  int s_ti = 0, s_tj = 0, s_cnt = 0;
  float s_mre = 0.f, s_mim = 0.f;

  __syncthreads(); // B3-equivalent for t=0

  for (int t = 0; t < TSTEPS; t++) {
    // per-step scalar: ivn = 1/max(||v||,1e-8)
    float ivn;
    {
      float tot = (red_sh[0] + red_sh[1]) + (red_sh[2] + red_sh[3]);
      ivn = 1.f / fmaxf(sqrtf(tot), 1e-8f);
    }

    // ==== [S] wave0: top-8 network + serial dynamics  ∥  workers ==========
    if (wid == 0) {
      // f64 prefix-merge network over the 256 per-thread maxima (4/lane).
      // Sorted top-8 thread-maxima == exact global top-8 unless some thread
      // holds >=2 of the top-8 elements (extras, handled below).
      uint2 q0 = lmax2[lane * 4 + 0], q1 = lmax2[lane * 4 + 1];
      uint2 q2 = lmax2[lane * 4 + 2], q3 = lmax2[lane * 4 + 3];
      double c[8];
      c[0] = __hiloint2double((int)q0.x, (int)q0.y);
      c[1] = __hiloint2double((int)q1.x, (int)q1.y);
      c[2] = __hiloint2double((int)q2.x, (int)q2.y);
      c[3] = __hiloint2double((int)q3.x, (int)q3.y);
      c[4] = 0.0; c[5] = 0.0; c[6] = 0.0; c[7] = 0.0;
      sort4d(c);
      merge_first4<0x111, 0xf>(c);
      merge_level<0x112, 0xf>(c);
      merge_level<0x114, 0xf>(c);
      merge_level<0x118, 0xf>(c);
      merge_level<0x142, 0xa>(c);
      merge_level<0x143, 0xc>(c); // lane63 = sorted top-8 maxima (with idx)
      // publish theta = 8th key (hi,lo), release
      int th_hi = rl63(__double2hiint(c[7]));
      int th_lo = rl63(__double2loint(c[7]));
      if (lane == 0) {
        theta_hi_sh = (unsigned int)th_hi;
        theta_lo_sh = (unsigned int)th_lo;
        __hip_atomic_store(&theta_flag, t + 1, __ATOMIC_RELEASE,
                           __HIP_MEMORY_SCOPE_WORKGROUP);
      }
      int toph[KTOP], topl[KTOP];
#pragma unroll
      for (int r = 0; r < KTOP; r++) {
        toph[r] = rl63(__double2hiint(c[r]));
        topl[r] = rl63(__double2loint(c[r]));
      }
      // wait for all 4 worker waves to report extras
      while (__hip_atomic_load(&extras_done, __ATOMIC_ACQUIRE,
                               __HIP_MEMORY_SCOPE_WORKGROUP) < 4 * (t + 1)) {
        __builtin_amdgcn_s_sleep(1);
      }
      int ec = extra_cnt;
      if (lane == 0) extra_cnt = 0; // reset for next step (barriers order it)
      if (ec > 0) {
        // rare path (~16%): merge top-8 maxima with extras via slot sort
        int ecc = ec; if (ecc > CCAP - 8) ecc = CCAP - 8;
        int khi = toph[0], klo = topl[0];
        if (lane == 1) { khi = toph[1]; klo = topl[1]; }
        if (lane == 2) { khi = toph[2]; klo = topl[2]; }
        if (lane == 3) { khi = toph[3]; klo = topl[3]; }
        if (lane == 4) { khi = toph[4]; klo = topl[4]; }
        if (lane == 5) { khi = toph[5]; klo = topl[5]; }
        if (lane == 6) { khi = toph[6]; klo = topl[6]; }
        if (lane == 7) { khi = toph[7]; klo = topl[7]; }
        if (lane < 8)
          cand_lds[lane] = ((unsigned long long)(unsigned int)khi << 32) |
                           (unsigned int)klo;
        int cnt = 8 + ecc;
        unsigned long long u0 = cand_lds[2 * lane];
        unsigned long long u1 = cand_lds[2 * lane + 1];
        double a = (2 * lane < cnt) ? __longlong_as_double((long long)u0) : 0.0;
        double b2 = (2 * lane + 1 < cnt) ? __longlong_as_double((long long)u1) : 0.0;
        double d[8];
        d[0] = fmax(a, b2); d[1] = fmin(a, b2);
        d[2] = 0.0; d[3] = 0.0; d[4] = 0.0; d[5] = 0.0; d[6] = 0.0; d[7] = 0.0;
        merge_2to4_d<0x111, 0xf>(d);  // sorted-4, covers slots 0-3
        merge_first4<0x112, 0xf>(d);  // covers slots 0-7
        int src = 3;
        if (cnt > 8)  { merge_level<0x114, 0xf>(d); src = 7;  }  // 0-15
        if (cnt > 16) { merge_level<0x118, 0xf>(d); src = 15; }  // 0-31
        if (cnt > 32) { merge_level<0x142, 0xa>(d); src = 31; }  // 0-63
        if (cnt > 64) { merge_level<0x143, 0xc>(d); src = 63; }  // 0-127
#pragma unroll
        for (int r = 0; r < KTOP; r++)
          topl[r] = __builtin_amdgcn_readlane(__double2loint(d[r]), src);
      }
      int top[KTOP];
#pragma unroll
      for (int r = 0; r < KTOP; r++) top[r] = ~topl[r];

      // ---- pair (ii,jj) for lane p, row-major triu order ----
      int pi = (lane < 28) ? lane : 27;
      int ii = 0, base = 0;
      if (pi >= 7)  { ii = 1; base = 7;  }
      if (pi >= 13) { ii = 2; base = 13; }
      if (pi >= 18) { ii = 3; base = 18; }
      if (pi >= 22) { ii = 4; base = 22; }
      if (pi >= 25) { ii = 5; base = 25; }
      if (pi >= 27) { ii = 6; base = 27; }
      int jj = ii + 1 + (pi - base);
      int gi = top[0];
      if (ii == 1) gi = top[1];
      if (ii == 2) gi = top[2];
      if (ii == 3) gi = top[3];
      if (ii == 4) gi = top[4];
      if (ii == 5) gi = top[5];
      if (ii == 6) gi = top[6];
      int gj = top[1];
      if (jj == 2) gj = top[2];
      if (jj == 3) gj = top[3];
      if (jj == 4) gj = top[4];
      if (jj == 5) gj = top[5];
      if (jj == 6) gj = top[6];
      if (jj == 7) gj = top[7];

      float4 c4i = sc4[gi], c4j = sc4[gj];
      float sri = c4i.y * ivn, sii2 = c4i.z * ivn;
      float srj = c4j.y * ivn, sij = c4j.z * ivn;
      float cri = c4i.x * sri, cii = c4i.x * sii2;
      float crj = c4j.x * srj, cij = c4j.x * sij;
      float score = cri * crj + cii * cij; // Re(c_i conj(c_j))
      bool valid = (lane < 28);
      bool pos = valid && (score > 0.f);
      unsigned long long posmask = __ballot(pos);
      int npos = __popcll(posmask);
      float pr = sri * srj - sii2 * sij;
      float pq = sri * sij + sii2 * srj;
      float ap = fmaxf(sqrtf(pr * pr + pq * pq), 1e-8f);
      float mr = (0.05f * pr) / ap, mi = (0.05f * pq) / ap;

      unsigned long long bmask = 0ull;
      if (npos > 0) {
        int nbind = (int)((float)npos * 0.15f);
        if (nbind < 1) nbind = 1;
        float val = pos ? score : -__builtin_inff();
        float th2 = 0.f;
        for (int k2 = 0; k2 < nbind; ++k2) {
          float mx = wave_max_f32(val);
          th2 = __int_as_float(rl63(__float_as_int(mx)));
          if (k2 + 1 < nbind) {
            unsigned long long em = __ballot(val == th2);
            if (lane == (int)__builtin_ctzll(em)) val = -__builtin_inff();
          }
        }
        bool bind = valid && (score >= th2);
        bmask = __ballot(bind);
      }
      // slot scan in pair order
      while (bmask) {
        int pp = (int)__builtin_ctzll(bmask);
        bmask &= bmask - 1;
        int pci = __builtin_amdgcn_readlane(gi, pp);
        int pcj = __builtin_amdgcn_readlane(gj, pp);
        int pmr = __builtin_amdgcn_readlane(__float_as_int(mr), pp);
        int pmi = __builtin_amdgcn_readlane(__float_as_int(mi), pp);
        bool isslot = (lane < MSLOT);
        bool match = isslot && (s_cnt > 0) &&
                     ((s_ti == pci && s_tj == pcj) ||
                      (s_ti == pcj && s_tj == pci));
        unsigned long long mm = __ballot(match);
        if (mm != 0ull) {
          if (lane == (int)__builtin_ctzll(mm)) s_cnt = 5; // refresh only
        } else {
          unsigned long long fm = __ballot(isslot && s_cnt <= 0);
          if (fm != 0ull && lane == (int)__builtin_ctzll(fm)) {
            s_ti = pci; s_tj = pcj;
            s_mre = __int_as_float(pmr); s_mim = __int_as_float(pmi);
            s_cnt = 5;
          }
        }
      }
      // decay + alive + scatter; dead slots add exact 0.0 -> skip atomics
      if (lane < MSLOT) {
        s_mre *= 0.9f; s_mim *= 0.9f; s_cnt -= 1;
        bool alive = (s_cnt > 0) &&
                     (sqrtf(s_mre * s_mre + s_mim * s_mim) > 1e-6f);
        if (!alive) { s_cnt = 0; s_mre = 0.f; s_mim = 0.f; }
        if (s_cnt > 0) {
          atomicAdd(&dxy[s_ti].x, 0.1f * s_mre);
          atomicAdd(&dxy[s_tj].x, 0.1f * s_mre);
          atomicAdd(&dxy[s_ti].y, 0.1f * s_mim);
          atomicAdd(&dxy[s_tj].y, 0.1f * s_mim);
        }
      }
    } else {
      // workers: overlapped with wave0's network + serial section
      if (t + 1 < TSTEPS) {
        const float *xr = xb + (size_t)(t + 1) * DIM_;
#pragma unroll
        for (int j = 0; j < EPT; j++) hnext[j] = xr[wtid + NWORK * j];
      }
#pragma unroll
      for (int j = 0; j < EPT; j++) {
        osr[j] = vre[j] * ivn; osi[j] = vim[j] * ivn;
      }
      if (t > 0) {
        float *op = out + ((size_t)b * TSTEPS + (t - 1)) * DIM_;
#pragma unroll
        for (int j = 0; j < EPT; j++)
          op[wtid + NWORK * j] = sqrtf(osr[j] * osr[j] + osi[j] * osi[j]);
      }
      // speculative update with delta = 0 (exact for untouched elements)
#pragma unroll
      for (int j = 0; j < EPT; j++) {
        float sri = osr[j], sii2 = osi[j];
        float h = hcur[j];
        float car = h * sri, cai = h * sii2;
        bool res = (car > 1e-6f) && (fabsf(cai) < car);
        bool tor = (car < -1e-6f) || (fabsf(cai) >= fabsf(car));
        float m1 = (res || tor) ? 1.f : 0.f;
        float mt = tor ? 1.f : 0.f;
        float ur = eta * (car * m1 + mt * tbre_[j]);
        float ui = eta * (cai * m1 + mt * tbim_[j]);
        vre[j] = sri + ur; vim[j] = sii2 + ui;
      }
      // acquire theta from wave0; append extras (non-max elements > theta)
      while (__hip_atomic_load(&theta_flag, __ATOMIC_ACQUIRE,
                               __HIP_MEMORY_SCOPE_WORKGROUP) < t + 1) {
        __builtin_amdgcn_s_sleep(1);
      }
      unsigned int th_hi = theta_hi_sh, th_lo = theta_lo_sh;
#pragma unroll
      for (int j = 0; j < EPT; j++) {
        unsigned int hb = (unsigned int)__float_as_int(av[j]);
        unsigned int lo = ~(unsigned int)(wtid + NWORK * j);
        bool isext = (hb > th_hi) || (hb == th_hi && lo > th_lo);
        if (isext && lo != lmlo) {
          int slot = atomicAdd(&extra_cnt, 1);
          if (8 + slot < CCAP)
            cand_lds[8 + slot] =
                ((unsigned long long)hb << 32) | (unsigned long long)lo;
        }
      }
      if (lane == 0)
        __hip_atomic_fetch_add(&extras_done, 1, __ATOMIC_RELEASE,
                               __HIP_MEMORY_SCOPE_WORKGROUP);
    }
    __syncthreads(); // B2: dxy ready

    // ============ [C] workers: patch + norm + prep(t+1) + maxima ==========
    if (wid > 0) {
      float2 dd[EPT];
#pragma unroll
      for (int j = 0; j < EPT; j++) dd[j] = dxy[wtid + NWORK * j];
      float acc2 = 0.f, lm = -1.f;
      lmlo = 0;
#pragma unroll
      for (int j = 0; j < EPT; j++) {
        int e = wtid + NWORK * j;
        if (dd[j].x != 0.f || dd[j].y != 0.f) {
          dxy[e] = make_float2(0.f, 0.f); // re-zero touched
          float ar = osr[j] + dd[j].x, ai = osi[j] + dd[j].y;
          float h = hcur[j];
          float car = h * ar, cai = h * ai;
          bool res = (car > 1e-6f) && (fabsf(cai) < car);
          bool tor = (car < -1e-6f) || (fabsf(cai) >= fabsf(car));
          float m1 = (res || tor) ? 1.f : 0.f;
          float mt = tor ? 1.f : 0.f;
          float ur = eta * (car * m1 + mt * tbre_[j]);
          float ui = eta * (cai * m1 + mt * tbim_[j]);
          vre[j] = osr[j] + ur; vim[j] = osi[j] + ui;
        }
        acc2 += vre[j] * vre[j] + vim[j] * vim[j];
        // prep(t+1): advance h, compute |c| key, track argmax, stage sc4
        float h = hnext[j];
        hcur[j] = h;
        float cr = h * vre[j], ci = h * vim[j];
        av[j] = sqrtf(cr * cr + ci * ci);
        unsigned int lo = ~(unsigned int)e;
        if (av[j] > lm || (av[j] == lm && lo > lmlo)) { lm = av[j]; lmlo = lo; }
        sc4[e] = make_float4(h, vre[j], vim[j], 0.f);
      }
      float ws = wave_sum_f32(acc2);
      if (lane == 63) red_sh[wid - 1] = ws;
      lmax2[wtid] = make_uint2((unsigned int)__float_as_int(lm), lmlo);
    }
    __syncthreads(); // B3: red_sh/lmax2/sc4/dxy-zero ready for t+1
  }

  // epilogue: final output row
  if (wid > 0) {
    float tot = (red_sh[0] + red_sh[1]) + (red_sh[2] + red_sh[3]);
    float ivnF = 1.f / fmaxf(sqrtf(tot), 1e-8f);
    float *op = out + ((size_t)b * TSTEPS + (TSTEPS - 1)) * DIM_;
#pragma unroll
    for (int j = 0; j < EPT; j++) {
      float sr = vre[j] * ivnF, si = vim[j] * ivnF;
      op[wtid + NWORK * j] = sqrtf(sr * sr + si * si);
    }
  }
}

extern "C" void kernel_launch(void *const *d_in, const int *in_sizes, int n_in,
                              void *d_out, int out_size, void *d_ws,
                              size_t ws_size, hipStream_t stream) {
  const float *x = (const float *)d_in[0];
  const float *tre = (const float *)d_in[1];
  const float *tim = (const float *)d_in[2];
  const float *eta = (const float *)d_in[3];
  const float *tbre = (const float *)d_in[4];
  const float *tbim = (const float *)d_in[5];
  float *out = (float *)d_out;
  me_fused<<<NB, NTHREADS, 0, stream>>>(x, tre, tim, eta, tbre, tbim, out);
}

// Round 7
// 1051.607 us; speedup vs baseline: 1.2810x; 1.2810x over previous
//
#include <hip/hip_runtime.h>
#include <math.h>

#define DIM_ 2048
#define KTOP 8
#define MSLOT 16
#define TSTEPS 256
#define NB 64
#define NTHREADS 576 // 9 waves: wave0 = serial wave, waves 1..8 = workers
#define NWORK 512
#define EPT 4
#define CCAP 128

static_assert(NWORK * EPT == DIM_, "mapping");

#define DPP0(src, ctrl, rm) __builtin_amdgcn_update_dpp(0, (src), (ctrl), (rm), 0xf, true)

// ---- f64 packed-key helpers (key = f32bits(|c|) : ~index, never NaN) ----
__device__ __forceinline__ void ced(double &a, double &b) {
  double mx = fmax(a, b);
  b = fmin(a, b);
  a = mx;
}

// merge own sorted-2 (k[0..1]) with partner's sorted-2 -> sorted-4 in k[0..3]
template <int CTRL, int RM>
__device__ __forceinline__ void merge_2to4_d(double k[8]) {
  int lo0 = DPP0(__double2loint(k[0]), CTRL, RM);
  int hi0 = DPP0(__double2hiint(k[0]), CTRL, RM);
  int lo1 = DPP0(__double2loint(k[1]), CTRL, RM);
  int hi1 = DPP0(__double2hiint(k[1]), CTRL, RM);
  double b0 = __hiloint2double(hi0, lo0);
  double b1 = __hiloint2double(hi1, lo1);
  double z2 = b1, z3 = b0; // bitonic: [k0,k1,b1,b0]
  ced(k[0], z2); ced(k[1], z3);
  ced(k[0], k[1]); ced(z2, z3);
  k[2] = z2; k[3] = z3;
}

// merge own sorted-4 (k[0..3]) with partner's sorted-4 -> sorted-8
template <int CTRL, int RM>
__device__ __forceinline__ void merge_first4(double k[8]) {
  double b[4];
#pragma unroll
  for (int i = 0; i < 4; i++) {
    int lo = DPP0(__double2loint(k[i]), CTRL, RM);
    int hi = DPP0(__double2hiint(k[i]), CTRL, RM);
    b[i] = __hiloint2double(hi, lo);
  }
  k[4] = b[3]; k[5] = b[2]; k[6] = b[1]; k[7] = b[0]; // bitonic sequence
  ced(k[0],k[4]); ced(k[1],k[5]); ced(k[2],k[6]); ced(k[3],k[7]);
  ced(k[0],k[2]); ced(k[1],k[3]); ced(k[4],k[6]); ced(k[5],k[7]);
  ced(k[0],k[1]); ced(k[2],k[3]); ced(k[4],k[5]); ced(k[6],k[7]);
}

// pull partner's sorted-8, keep top-8 of union, resort desc
template <int CTRL, int RM>
__device__ __forceinline__ void merge_level(double k[8]) {
  double b[8];
#pragma unroll
  for (int i = 0; i < 8; i++) {
    int lo = DPP0(__double2loint(k[i]), CTRL, RM);
    int hi = DPP0(__double2hiint(k[i]), CTRL, RM);
    b[i] = __hiloint2double(hi, lo);
  }
#pragma unroll
  for (int i = 0; i < 8; i++) k[i] = fmax(k[i], b[7 - i]);
  ced(k[0],k[4]); ced(k[1],k[5]); ced(k[2],k[6]); ced(k[3],k[7]);
  ced(k[0],k[2]); ced(k[1],k[3]); ced(k[4],k[6]); ced(k[5],k[7]);
  ced(k[0],k[1]); ced(k[2],k[3]); ced(k[4],k[5]); ced(k[6],k[7]);
}

// ---- f32 list network (theta = 8th largest of 512 per-thread maxima) ----
__device__ __forceinline__ void cedf(float &a, float &b) {
  float mx = fmaxf(a, b);
  b = fminf(a, b);
  a = mx;
}
// Batcher odd-even mergesort, 8 elements, descending (19 CE)
__device__ __forceinline__ void sort8f(float k[8]) {
  cedf(k[0],k[1]); cedf(k[2],k[3]); cedf(k[4],k[5]); cedf(k[6],k[7]);
  cedf(k[0],k[2]); cedf(k[1],k[3]); cedf(k[4],k[6]); cedf(k[5],k[7]);
  cedf(k[1],k[2]); cedf(k[5],k[6]);
  cedf(k[0],k[4]); cedf(k[1],k[5]); cedf(k[2],k[6]); cedf(k[3],k[7]);
  cedf(k[2],k[4]); cedf(k[3],k[5]);
  cedf(k[1],k[2]); cedf(k[3],k[4]); cedf(k[5],k[6]);
}
template <int CTRL, int RM>
__device__ __forceinline__ void merge_level_f32(float k[8]) {
  float b[8];
#pragma unroll
  for (int i = 0; i < 8; i++)
    b[i] = __int_as_float(DPP0(__float_as_int(k[i]), CTRL, RM));
#pragma unroll
  for (int i = 0; i < 8; i++) k[i] = fmaxf(k[i], b[7 - i]);
  cedf(k[0],k[4]); cedf(k[1],k[5]); cedf(k[2],k[6]); cedf(k[3],k[7]);
  cedf(k[0],k[2]); cedf(k[1],k[3]); cedf(k[4],k[6]); cedf(k[5],k[7]);
  cedf(k[0],k[1]); cedf(k[2],k[3]); cedf(k[4],k[5]); cedf(k[6],k[7]);
}

#define FMAX_STAGE(x, ctrl, rm)                                                \
  x = fmaxf(x, __int_as_float(DPP0(__float_as_int(x), ctrl, rm)))
#define FADD_STAGE(x, ctrl, rm)                                                \
  x = x + __int_as_float(DPP0(__float_as_int(x), ctrl, rm))

__device__ __forceinline__ float wave_max_f32(float x) {
  FMAX_STAGE(x, 0x111, 0xf);
  FMAX_STAGE(x, 0x112, 0xf);
  FMAX_STAGE(x, 0x114, 0xf);
  FMAX_STAGE(x, 0x118, 0xf);
  FMAX_STAGE(x, 0x142, 0xa);
  FMAX_STAGE(x, 0x143, 0xc);
  return x; // lane 63 has the max
}
__device__ __forceinline__ float wave_sum_f32(float x) {
  FADD_STAGE(x, 0x111, 0xf);
  FADD_STAGE(x, 0x112, 0xf);
  FADD_STAGE(x, 0x114, 0xf);
  FADD_STAGE(x, 0x118, 0xf);
  FADD_STAGE(x, 0x142, 0xa);
  FADD_STAGE(x, 0x143, 0xc);
  return x; // lane 63 has the sum
}
__device__ __forceinline__ int rl63(int v) {
  return __builtin_amdgcn_readlane(v, 63);
}

__global__ void __launch_bounds__(NTHREADS)
me_fused(const float *__restrict__ x, const float *__restrict__ tape_re,
         const float *__restrict__ tape_im, const float *__restrict__ eta_param,
         const float *__restrict__ tbias_re, const float *__restrict__ tbias_im,
         float *__restrict__ out) {
  __shared__ float4 sc4[DIM_];                 // (h, vre, vim, 0)
  __shared__ float2 dxy[DIM_];                 // scatter deltas
  __shared__ float4 lmax4[NWORK / 4];          // 512 per-thread |c| maxima
  __shared__ unsigned long long cand_lds[CCAP];// candidate keys (f64 packed)
  __shared__ int ccnt;                         // candidate count
  __shared__ float red_sh[8];                  // norm^2 partials

  const int tid = threadIdx.x;
  const int lane = tid & 63;
  const int wid = tid >> 6;
  const int wtid = tid - 64; // worker element base (valid for wid>0)
  const int b = blockIdx.x;

  const float eta = fabsf(eta_param[0]);

  // worker state (unnormalized v; ivn applied per step)
  float vre[EPT], vim[EPT], tbre_[EPT], tbim_[EPT];
  float hcur[EPT], hnext[EPT], av[EPT];
  float osr[EPT], osi[EPT];
  const float *xb = x + (size_t)b * TSTEPS * DIM_;

  if (wid > 0) {
    float acc = 0.f, lm = 0.f;
#pragma unroll
    for (int j = 0; j < EPT; j++) {
      int e = wtid + NWORK * j;
      float a = tape_re[e], c2 = tape_im[e];
      vre[j] = a; vim[j] = c2;
      tbre_[j] = tbias_re[e]; tbim_[j] = tbias_im[e];
      float h = xb[e];
      hcur[j] = h; hnext[j] = h;
      dxy[e] = make_float2(0.f, 0.f);
      acc += a * a + c2 * c2;
      // prep(0): scale-invariant key magnitude + staging
      float cr = h * a, ci = h * c2;
      av[j] = sqrtf(cr * cr + ci * ci);
      lm = fmaxf(lm, av[j]);
      sc4[e] = make_float4(h, a, c2, 0.f);
    }
    float ws = wave_sum_f32(acc);
    if (lane == 63) red_sh[wid - 1] = ws;
    ((float *)lmax4)[wtid] = lm;
  }
  if (tid == 0) ccnt = 0;

  // transient slots live in wave0 registers (lanes 0..15)
  int s_ti = 0, s_tj = 0, s_cnt = 0;
  float s_mre = 0.f, s_mim = 0.f;

  __syncthreads(); // B3 equivalent for t=0

  for (int t = 0; t < TSTEPS; t++) {
    // per-step scalar: ivn = 1/max(||v||,1e-8)  (red_sh from prep/[C])
    float ivn;
    {
      float tot = ((red_sh[0] + red_sh[1]) + (red_sh[2] + red_sh[3])) +
                  ((red_sh[4] + red_sh[5]) + (red_sh[6] + red_sh[7]));
      ivn = 1.f / fmaxf(sqrtf(tot), 1e-8f);
    }

    // ============ [A] workers: theta + candidate extraction ONLY ==========
    if (wid > 0) {
      // theta = 8th largest of the 512 per-thread maxima (f32 network)
      float4 qa = lmax4[lane];
      float4 qb = lmax4[64 + lane];
      float k[8];
      k[0] = qa.x; k[1] = qa.y; k[2] = qa.z; k[3] = qa.w;
      k[4] = qb.x; k[5] = qb.y; k[6] = qb.z; k[7] = qb.w;
      sort8f(k);
      merge_level_f32<0x111, 0xf>(k);
      merge_level_f32<0x112, 0xf>(k);
      merge_level_f32<0x114, 0xf>(k);
      merge_level_f32<0x118, 0xf>(k);
      merge_level_f32<0x142, 0xa>(k);
      merge_level_f32<0x143, 0xc>(k);
      float th = __int_as_float(rl63(__float_as_int(k[7])));
      // extract candidates (guaranteed: 8 <= cnt; typically 8-10)
#pragma unroll
      for (int j = 0; j < EPT; j++) {
        if (av[j] >= th) {
          int e = wtid + NWORK * j;
          int slot = atomicAdd(&ccnt, 1);
          if (slot < CCAP)
            cand_lds[slot] = (unsigned long long)__double_as_longlong(
                __hiloint2double(__float_as_int(av[j]), ~e));
        }
      }
    }
    __syncthreads(); // B1: candidates ready

    // ==== [S] wave0 serial dynamics  ∥  workers: prefetch/out/spec ========
    if (wid == 0) {
      int cnt = ccnt;
      if (lane == 0) ccnt = 0; // reset (next append after B2+B3)
      if (cnt > CCAP) cnt = CCAP;
      // load 2 candidates per lane: slots 2*lane, 2*lane+1
      unsigned long long u0 = cand_lds[2 * lane];
      unsigned long long u1 = cand_lds[2 * lane + 1];
      double a = (2 * lane < cnt) ? __longlong_as_double((long long)u0) : 0.0;
      double b2 = (2 * lane + 1 < cnt) ? __longlong_as_double((long long)u1) : 0.0;
      double c[8];
      c[0] = fmax(a, b2); c[1] = fmin(a, b2);
      c[2] = 0.0; c[3] = 0.0; c[4] = 0.0; c[5] = 0.0; c[6] = 0.0; c[7] = 0.0;
      merge_2to4_d<0x111, 0xf>(c);  // sorted-4, lane1 covers slots 0-3
      merge_first4<0x112, 0xf>(c);  // lane3 covers slots 0-7
      int src = 3;
      if (cnt > 8)  { merge_level<0x114, 0xf>(c); src = 7;  }  // 0-15
      if (cnt > 16) { merge_level<0x118, 0xf>(c); src = 15; }  // 0-31
      if (cnt > 32) { merge_level<0x142, 0xa>(c); src = 31; }  // 0-63
      if (cnt > 64) { merge_level<0x143, 0xc>(c); src = 63; }  // 0-127
      int top[KTOP];
#pragma unroll
      for (int r = 0; r < KTOP; r++)
        top[r] = ~__builtin_amdgcn_readlane(__double2loint(c[r]), src);

      // ---- pair (ii,jj) for lane p, row-major triu order ----
      int pi = (lane < 28) ? lane : 27;
      int ii = 0, base = 0;
      if (pi >= 7)  { ii = 1; base = 7;  }
      if (pi >= 13) { ii = 2; base = 13; }
      if (pi >= 18) { ii = 3; base = 18; }
      if (pi >= 22) { ii = 4; base = 22; }
      if (pi >= 25) { ii = 5; base = 25; }
      if (pi >= 27) { ii = 6; base = 27; }
      int jj = ii + 1 + (pi - base);
      int gi = top[0];
      if (ii == 1) gi = top[1];
      if (ii == 2) gi = top[2];
      if (ii == 3) gi = top[3];
      if (ii == 4) gi = top[4];
      if (ii == 5) gi = top[5];
      if (ii == 6) gi = top[6];
      int gj = top[1];
      if (jj == 2) gj = top[2];
      if (jj == 3) gj = top[3];
      if (jj == 4) gj = top[4];
      if (jj == 5) gj = top[5];
      if (jj == 6) gj = top[6];
      if (jj == 7) gj = top[7];

      float4 c4i = sc4[gi], c4j = sc4[gj];
      float sri = c4i.y * ivn, sii2 = c4i.z * ivn;
      float srj = c4j.y * ivn, sij = c4j.z * ivn;
      float cri = c4i.x * sri, cii = c4i.x * sii2;
      float crj = c4j.x * srj, cij = c4j.x * sij;
      float score = cri * crj + cii * cij; // Re(c_i conj(c_j))
      bool valid = (lane < 28);
      bool pos = valid && (score > 0.f);
      unsigned long long posmask = __ballot(pos);
      int npos = __popcll(posmask);
      float pr = sri * srj - sii2 * sij;
      float pq = sri * sij + sii2 * srj;
      float ap = fmaxf(sqrtf(pr * pr + pq * pq), 1e-8f);
      float mr = (0.05f * pr) / ap, mi = (0.05f * pq) / ap;

      unsigned long long bmask = 0ull;
      if (npos > 0) {
        int nbind = (int)((float)npos * 0.15f);
        if (nbind < 1) nbind = 1;
        float val = pos ? score : -__builtin_inff();
        float th2 = 0.f;
        for (int k2 = 0; k2 < nbind; ++k2) {
          float mx = wave_max_f32(val);
          th2 = __int_as_float(rl63(__float_as_int(mx)));
          if (k2 + 1 < nbind) {
            unsigned long long em = __ballot(val == th2);
            if (lane == (int)__builtin_ctzll(em)) val = -__builtin_inff();
          }
        }
        bool bind = valid && (score >= th2);
        bmask = __ballot(bind);
      }
      // slot scan in pair order
      while (bmask) {
        int pp = (int)__builtin_ctzll(bmask);
        bmask &= bmask - 1;
        int pci = __builtin_amdgcn_readlane(gi, pp);
        int pcj = __builtin_amdgcn_readlane(gj, pp);
        int pmr = __builtin_amdgcn_readlane(__float_as_int(mr), pp);
        int pmi = __builtin_amdgcn_readlane(__float_as_int(mi), pp);
        bool isslot = (lane < MSLOT);
        bool match = isslot && (s_cnt > 0) &&
                     ((s_ti == pci && s_tj == pcj) ||
                      (s_ti == pcj && s_tj == pci));
        unsigned long long mm = __ballot(match);
        if (mm != 0ull) {
          if (lane == (int)__builtin_ctzll(mm)) s_cnt = 5; // refresh only
        } else {
          unsigned long long fm = __ballot(isslot && s_cnt <= 0);
          if (fm != 0ull && lane == (int)__builtin_ctzll(fm)) {
            s_ti = pci; s_tj = pcj;
            s_mre = __int_as_float(pmr); s_mim = __int_as_float(pmi);
            s_cnt = 5;
          }
        }
      }
      // decay + alive + scatter; dead slots add exact 0.0 -> skip atomics
      if (lane < MSLOT) {
        s_mre *= 0.9f; s_mim *= 0.9f; s_cnt -= 1;
        bool alive = (s_cnt > 0) &&
                     (sqrtf(s_mre * s_mre + s_mim * s_mim) > 1e-6f);
        if (!alive) { s_cnt = 0; s_mre = 0.f; s_mim = 0.f; }
        if (s_cnt > 0) {
          atomicAdd(&dxy[s_ti].x, 0.1f * s_mre);
          atomicAdd(&dxy[s_tj].x, 0.1f * s_mre);
          atomicAdd(&dxy[s_ti].y, 0.1f * s_mim);
          atomicAdd(&dxy[s_tj].y, 0.1f * s_mim);
        }
      }
    } else {
      // ============ workers overlap wave0's serial section ============
      if (t + 1 < TSTEPS) {
        const float *xr = xb + (size_t)(t + 1) * DIM_;
#pragma unroll
        for (int j = 0; j < EPT; j++) hnext[j] = xr[wtid + NWORK * j];
      }
#pragma unroll
      for (int j = 0; j < EPT; j++) {
        osr[j] = vre[j] * ivn; osi[j] = vim[j] * ivn;
      }
      if (t > 0) {
        float *op = out + ((size_t)b * TSTEPS + (t - 1)) * DIM_;
#pragma unroll
        for (int j = 0; j < EPT; j++)
          op[wtid + NWORK * j] = sqrtf(osr[j] * osr[j] + osi[j] * osi[j]);
      }
      // speculative update with delta = 0 (exact for untouched elements)
#pragma unroll
      for (int j = 0; j < EPT; j++) {
        float sri = osr[j], sii2 = osi[j];
        float h = hcur[j];
        float car = h * sri, cai = h * sii2;
        bool res = (car > 1e-6f) && (fabsf(cai) < car);
        bool tor = (car < -1e-6f) || (fabsf(cai) >= fabsf(car));
        float m1 = (res || tor) ? 1.f : 0.f;
        float mt = tor ? 1.f : 0.f;
        float ur = eta * (car * m1 + mt * tbre_[j]);
        float ui = eta * (cai * m1 + mt * tbim_[j]);
        vre[j] = sri + ur; vim[j] = sii2 + ui;
      }
    }
    __syncthreads(); // B2: dxy ready

    // ============ [C] workers: sparse patch + norm + prep(t+1) =============
    if (wid > 0) {
      float2 dd[EPT];
#pragma unroll
      for (int j = 0; j < EPT; j++) dd[j] = dxy[wtid + NWORK * j];
      float acc2 = 0.f, lm = 0.f;
#pragma unroll
      for (int j = 0; j < EPT; j++) {
        int e = wtid + NWORK * j;
        if (dd[j].x != 0.f || dd[j].y != 0.f) {
          dxy[e] = make_float2(0.f, 0.f); // re-zero touched
          float ar = osr[j] + dd[j].x, ai = osi[j] + dd[j].y;
          float h = hcur[j];
          float car = h * ar, cai = h * ai;
          bool res = (car > 1e-6f) && (fabsf(cai) < car);
          bool tor = (car < -1e-6f) || (fabsf(cai) >= fabsf(car));
          float m1 = (res || tor) ? 1.f : 0.f;
          float mt = tor ? 1.f : 0.f;
          float ur = eta * (car * m1 + mt * tbre_[j]);
          float ui = eta * (cai * m1 + mt * tbim_[j]);
          vre[j] = osr[j] + ur; vim[j] = osi[j] + ui;
        }
        acc2 += vre[j] * vre[j] + vim[j] * vim[j];
        // prep(t+1): advance h, compute |c| key magnitude, stage sc4
        float h = hnext[j];
        hcur[j] = h;
        float cr = h * vre[j], ci = h * vim[j];
        av[j] = sqrtf(cr * cr + ci * ci);
        lm = fmaxf(lm, av[j]);
        sc4[e] = make_float4(h, vre[j], vim[j], 0.f);
      }
      float ws = wave_sum_f32(acc2);
      if (lane == 63) red_sh[wid - 1] = ws;
      ((float *)lmax4)[wtid] = lm;
    }
    __syncthreads(); // B3: lmax/sc4/red_sh ready for t+1
  }

  // epilogue: final output row
  if (wid > 0) {
    float tot = ((red_sh[0] + red_sh[1]) + (red_sh[2] + red_sh[3])) +
                ((red_sh[4] + red_sh[5]) + (red_sh[6] + red_sh[7]));
    float ivnF = 1.f / fmaxf(sqrtf(tot), 1e-8f);
    float *op = out + ((size_t)b * TSTEPS + (TSTEPS - 1)) * DIM_;
#pragma unroll
    for (int j = 0; j < EPT; j++) {
      float sr = vre[j] * ivnF, si = vim[j] * ivnF;
      op[wtid + NWORK * j] = sqrtf(sr * sr + si * si);
    }
  }
}

extern "C" void kernel_launch(void *const *d_in, const int *in_sizes, int n_in,
                              void *d_out, int out_size, void *d_ws,
                              size_t ws_size, hipStream_t stream) {
  const float *x = (const float *)d_in[0];
  const float *tre = (const float *)d_in[1];
  const float *tim = (const float *)d_in[2];
  const float *eta = (const float *)d_in[3];
  const float *tbre = (const float *)d_in[4];
  const float *tbim = (const float *)d_in[5];
  float *out = (float *)d_out;
  me_fused<<<NB, NTHREADS, 0, stream>>>(x, tre, tim, eta, tbre, tbim, out);
}